// Round 9
// baseline (252.344 us; speedup 1.0000x reference)
//
#include <hip/hip_runtime.h>
#include <hip/hip_fp16.h>
#include <math.h>

#define B   16
#define C   256
#define HW  16384   // 128*128
#define HW4 4096    // HW/4
#define HW8 2048    // HW/8
#define NCHUNK 4    // channel chunks in spatial-stats pass (64 ch each)

typedef float vf4 __attribute__((ext_vector_type(4)));
typedef unsigned int vu4 __attribute__((ext_vector_type(4)));
typedef unsigned int vu2 __attribute__((ext_vector_type(2)));

__device__ __forceinline__ float2 h2f(unsigned int w) {
    __half2 h = *(const __half2*)&w;
    return __half22float2(h);
}

__device__ __forceinline__ float wave_reduce_sum(float v) {
    #pragma unroll
    for (int o = 32; o > 0; o >>= 1) v += __shfl_down(v, o, 64);
    return v;
}
__device__ __forceinline__ float wave_reduce_max(float v) {
    #pragma unroll
    for (int o = 32; o > 0; o >>= 1) v = fmaxf(v, __shfl_down(v, o, 64));
    return v;
}

// Pass 1: per-(b,c) sum & max over fp32 x (exact, NT loads), AND write fp16 copy.
__global__ __launch_bounds__(256) void k_chan_stats_cast(const float* __restrict__ x,
                                                         vu2* __restrict__ x16,
                                                         float* __restrict__ avg,
                                                         float* __restrict__ mx) {
    const int bc  = blockIdx.x;                 // 0..4095
    const int tid = threadIdx.x;
    const vf4* x4 = (const vf4*)x + (size_t)bc * HW4;
    vu2* o = x16 + (size_t)bc * HW4;
    float s = 0.f, m = -INFINITY;
    #pragma unroll
    for (int i = 0; i < 16; ++i) {
        vf4 v = __builtin_nontemporal_load(&x4[tid + i * 256]);
        s += (v.x + v.y) + (v.z + v.w);
        m = fmaxf(m, fmaxf(fmaxf(v.x, v.y), fmaxf(v.z, v.w)));
        __half2 lo = __halves2half2(__float2half_rn(v.x), __float2half_rn(v.y));
        __half2 hi = __halves2half2(__float2half_rn(v.z), __float2half_rn(v.w));
        vu2 u;
        u.x = *(const unsigned int*)&lo;
        u.y = *(const unsigned int*)&hi;
        o[tid + i * 256] = u;
    }
    s = wave_reduce_sum(s);
    m = wave_reduce_max(m);
    __shared__ float ss[4], sm[4];
    const int wid = tid >> 6, lane = tid & 63;
    if (lane == 0) { ss[wid] = s; sm[wid] = m; }
    __syncthreads();
    if (tid == 0) {
        float S = ss[0] + ss[1] + ss[2] + ss[3];
        float M = fmaxf(fmaxf(sm[0], sm[1]), fmaxf(sm[2], sm[3]));
        avg[bc] = S * (1.0f / HW);
        mx[bc]  = M;
    }
}

// Pass 2: bottleneck MLP. 16 lanes per hidden unit + shfl reduce.
__global__ __launch_bounds__(256) void k_mlp(const float* __restrict__ avg,
                                             const float* __restrict__ mx,
                                             const float* __restrict__ w1,   // [16,256]
                                             const float* __restrict__ w2,   // [256,16]
                                             float* __restrict__ chatt) {
    const int b = blockIdx.x, tid = threadIdx.x;
    __shared__ float sa[C], sx[C], h[16];
    sa[tid] = avg[b * C + tid];
    sx[tid] = mx[b * C + tid];
    __syncthreads();
    const int j = tid >> 4, sub = tid & 15;     // hidden unit j, lane-slice sub
    float pa = 0.f, pm = 0.f;
    #pragma unroll
    for (int c2 = sub; c2 < C; c2 += 16) {
        float w = w1[j * C + c2];
        pa += sa[c2] * w;
        pm += sx[c2] * w;
    }
    #pragma unroll
    for (int o = 8; o > 0; o >>= 1) {
        pa += __shfl_down(pa, o, 16);
        pm += __shfl_down(pm, o, 16);
    }
    if (sub == 0) h[j] = fmaxf(pa, 0.f) + fmaxf(pm, 0.f);
    __syncthreads();
    float o = 0.f;
    #pragma unroll
    for (int jj = 0; jj < 16; ++jj) o += h[jj] * w2[tid * 16 + jj];
    chatt[b * C + tid] = 1.0f / (1.0f + expf(-o));
}

// Pass 3: partial spatial mean/max over a 64-channel chunk of fp16 x * ch_att.
__global__ __launch_bounds__(256) void k_sp_partial(const vu4* __restrict__ x16,
                                                    const float* __restrict__ chatt,
                                                    float* __restrict__ pavg,
                                                    float* __restrict__ pmax) {
    const int blk   = blockIdx.x;
    const int chunk = blk & 3;
    const int tile  = (blk >> 2) & 7;
    const int b     = blk >> 5;
    const int tid   = threadIdx.x;
    const int g     = tile * 256 + tid;            // pixel-group (8 px), 0..2047
    float s[8];
    float m[8];
    #pragma unroll
    for (int k = 0; k < 8; ++k) { s[k] = 0.f; m[k] = -INFINITY; }
    const int c0 = chunk * 64;
    #pragma unroll 4
    for (int c = c0; c < c0 + 64; ++c) {
        vu4 u = x16[((size_t)(b * C + c)) * HW8 + g];
        const float a = chatt[b * C + c];
        #pragma unroll
        for (int q = 0; q < 4; ++q) {
            float2 f = h2f(u[q]);
            float y0 = f.x * a, y1 = f.y * a;
            s[2*q]   += y0;  s[2*q+1] += y1;
            m[2*q]   = fmaxf(m[2*q],   y0);
            m[2*q+1] = fmaxf(m[2*q+1], y1);
        }
    }
    vf4* pa = (vf4*)(pavg + ((size_t)(chunk * B + b)) * HW + g * 8);
    vf4* pm = (vf4*)(pmax + ((size_t)(chunk * B + b)) * HW + g * 8);
    vf4 a0 = {s[0], s[1], s[2], s[3]};
    vf4 a1 = {s[4], s[5], s[6], s[7]};
    vf4 m0 = {m[0], m[1], m[2], m[3]};
    vf4 m1 = {m[4], m[5], m[6], m[7]};
    pa[0] = a0; pa[1] = a1;
    pm[0] = m0; pm[1] = m1;
}

// Pass 4 (fused combine + 7x7 conv + sigmoid): each block produces a 16x16
// spatt tile from a 22x22 halo of combined maps (OOB = 0, zero-pad conv).
__global__ __launch_bounds__(256) void k_comb_conv(const float* __restrict__ pavg,
                                                   const float* __restrict__ pmax,
                                                   const float* __restrict__ wc,  // [1,2,7,7]
                                                   float* __restrict__ spatt) {
    const int blk = blockIdx.x;
    const int tx = blk & 7, ty = (blk >> 3) & 7, b = blk >> 6;
    __shared__ float sa[22][24], sm[22][24], swc[98];
    if (threadIdx.x < 98) swc[threadIdx.x] = wc[threadIdx.x];
    for (int idx = threadIdx.x; idx < 484; idx += 256) {
        const int ly = idx / 22, lx = idx - ly * 22;
        const int gy = ty * 16 + ly - 3, gx = tx * 16 + lx - 3;
        float s = 0.f, m = 0.f;
        if (gy >= 0 && gy < 128 && gx >= 0 && gx < 128) {
            const int p = gy * 128 + gx;
            float mm = -INFINITY;
            float ss = 0.f;
            #pragma unroll
            for (int ch = 0; ch < NCHUNK; ++ch) {
                ss += pavg[(size_t)(ch * B + b) * HW + p];
                mm = fmaxf(mm, pmax[(size_t)(ch * B + b) * HW + p]);
            }
            s = ss * (1.0f / C);
            m = mm;
        }
        sa[ly][lx] = s;
        sm[ly][lx] = m;
    }
    __syncthreads();
    const int px = threadIdx.x & 15, py = threadIdx.x >> 4;
    float acc = 0.f;
    #pragma unroll
    for (int kh = 0; kh < 7; ++kh) {
        #pragma unroll
        for (int kw = 0; kw < 7; ++kw) {
            acc += sa[py + kh][px + kw] * swc[kh * 7 + kw]
                 + sm[py + kh][px + kw] * swc[49 + kh * 7 + kw];
        }
    }
    spatt[(size_t)b * HW + (ty * 16 + py) * 128 + tx * 16 + px] =
        1.0f / (1.0f + expf(-acc));
}

// Pass 5 (ILP redesign): block <-> (b, pixel-tile, 32-ch group). spatt tile
// lives in registers for the whole block (reused across 32 channels); 8 NT
// loads kept in flight per thread; NT stores (out never re-read).
__global__ __launch_bounds__(256) void k_final(const vu4* __restrict__ x16,
                                               const float* __restrict__ chatt,
                                               const vf4* __restrict__ spatt,
                                               vf4* __restrict__ out) {
    const int blk  = blockIdx.x;
    const int cg   = blk & 7;                    // 32-channel group
    const int tile = (blk >> 3) & 7;             // pixel tile (2048 px)
    const int b    = blk >> 6;
    const int tid  = threadIdx.x;
    const int g    = tile * 256 + tid;           // pixel-group (8 px), 0..2047

    __shared__ float att[32];
    if (tid < 32) att[tid] = chatt[b * C + cg * 32 + tid];
    __syncthreads();

    const vf4 sp0 = spatt[(size_t)b * HW4 + g * 2];
    const vf4 sp1 = spatt[(size_t)b * HW4 + g * 2 + 1];

    const vu4* xb = x16 + ((size_t)(b * C + cg * 32)) * HW8 + g;
    vf4* ob = out + ((size_t)(b * C + cg * 32)) * HW4 + (size_t)g * 2;

    for (int cc = 0; cc < 32; cc += 8) {
        vu4 u[8];
        #pragma unroll
        for (int k = 0; k < 8; ++k)
            u[k] = __builtin_nontemporal_load(&xb[(size_t)(cc + k) * HW8]);
        #pragma unroll
        for (int k = 0; k < 8; ++k) {
            const float a = att[cc + k];
            float2 f0 = h2f(u[k].x);
            float2 f1 = h2f(u[k].y);
            float2 f2 = h2f(u[k].z);
            float2 f3 = h2f(u[k].w);
            vf4 r0 = {f0.x * a * sp0.x, f0.y * a * sp0.y,
                      f1.x * a * sp0.z, f1.y * a * sp0.w};
            vf4 r1 = {f2.x * a * sp1.x, f2.y * a * sp1.y,
                      f3.x * a * sp1.z, f3.y * a * sp1.w};
            __builtin_nontemporal_store(r0, &ob[(size_t)(cc + k) * HW4]);
            __builtin_nontemporal_store(r1, &ob[(size_t)(cc + k) * HW4 + 1]);
        }
    }
}

extern "C" void kernel_launch(void* const* d_in, const int* in_sizes, int n_in,
                              void* d_out, int out_size, void* d_ws, size_t ws_size,
                              hipStream_t stream) {
    const float* x  = (const float*)d_in[0];
    const float* w1 = (const float*)d_in[1];
    const float* w2 = (const float*)d_in[2];
    const float* wc = (const float*)d_in[3];
    vf4* out = (vf4*)d_out;
    char* ws = (char*)d_ws;

    // workspace layout
    vu2* x16  = (vu2*)ws;                                   // 128 MiB
    char* p = ws + (size_t)B * C * HW * 2;
    float* avg   = (float*)p;            p += 4096 * 4;     // [B,C]
    float* mx    = (float*)p;            p += 4096 * 4;
    float* chatt = (float*)p;            p += 4096 * 4;
    float* pavg  = (float*)p;            p += (size_t)NCHUNK * B * HW * 4;   // 4 MiB
    float* pmax  = (float*)p;            p += (size_t)NCHUNK * B * HW * 4;   // 4 MiB
    float* spatt = (float*)p;            p += (size_t)B * HW * 4;            // 1 MiB

    k_chan_stats_cast<<<B * C, 256, 0, stream>>>(x, x16, avg, mx);
    k_mlp<<<B, 256, 0, stream>>>(avg, mx, w1, w2, chatt);
    k_sp_partial<<<512, 256, 0, stream>>>((const vu4*)x16, chatt, pavg, pmax);
    k_comb_conv<<<1024, 256, 0, stream>>>(pavg, pmax, wc, spatt);
    k_final<<<1024, 256, 0, stream>>>((const vu4*)x16, chatt,
                                      (const vf4*)spatt, (vf4*)out);
}

// Round 10
// 189.543 us; speedup vs baseline: 1.3313x; 1.3313x over previous
//
#include <hip/hip_runtime.h>
#include <hip/hip_fp16.h>
#include <math.h>

#define B   16
#define C   256
#define HW  16384   // 128*128
#define HW4 4096    // HW/4
#define HW8 2048    // HW/8
#define NCHUNK 4    // channel chunks in spatial-stats pass (64 ch each)

typedef float vf4 __attribute__((ext_vector_type(4)));
typedef unsigned int vu4 __attribute__((ext_vector_type(4)));
typedef unsigned int vu2 __attribute__((ext_vector_type(2)));

__device__ __forceinline__ float2 h2f(unsigned int w) {
    __half2 h = *(const __half2*)&w;
    return __half22float2(h);
}

__device__ __forceinline__ float wave_reduce_sum(float v) {
    #pragma unroll
    for (int o = 32; o > 0; o >>= 1) v += __shfl_down(v, o, 64);
    return v;
}
__device__ __forceinline__ float wave_reduce_max(float v) {
    #pragma unroll
    for (int o = 32; o > 0; o >>= 1) v = fmaxf(v, __shfl_down(v, o, 64));
    return v;
}

// Pass 1: per-(b,c) sum & max over fp32 x (exact, NT loads), AND write fp16 copy.
__global__ __launch_bounds__(256) void k_chan_stats_cast(const float* __restrict__ x,
                                                         vu2* __restrict__ x16,
                                                         float* __restrict__ avg,
                                                         float* __restrict__ mx) {
    const int bc  = blockIdx.x;                 // 0..4095
    const int tid = threadIdx.x;
    const vf4* x4 = (const vf4*)x + (size_t)bc * HW4;
    vu2* o = x16 + (size_t)bc * HW4;
    float s = 0.f, m = -INFINITY;
    #pragma unroll
    for (int i = 0; i < 16; ++i) {
        vf4 v = __builtin_nontemporal_load(&x4[tid + i * 256]);
        s += (v.x + v.y) + (v.z + v.w);
        m = fmaxf(m, fmaxf(fmaxf(v.x, v.y), fmaxf(v.z, v.w)));
        __half2 lo = __halves2half2(__float2half_rn(v.x), __float2half_rn(v.y));
        __half2 hi = __halves2half2(__float2half_rn(v.z), __float2half_rn(v.w));
        vu2 u;
        u.x = *(const unsigned int*)&lo;
        u.y = *(const unsigned int*)&hi;
        o[tid + i * 256] = u;
    }
    s = wave_reduce_sum(s);
    m = wave_reduce_max(m);
    __shared__ float ss[4], sm[4];
    const int wid = tid >> 6, lane = tid & 63;
    if (lane == 0) { ss[wid] = s; sm[wid] = m; }
    __syncthreads();
    if (tid == 0) {
        float S = ss[0] + ss[1] + ss[2] + ss[3];
        float M = fmaxf(fmaxf(sm[0], sm[1]), fmaxf(sm[2], sm[3]));
        avg[bc] = S * (1.0f / HW);
        mx[bc]  = M;
    }
}

// Pass 2: bottleneck MLP. 16 lanes per hidden unit + shfl reduce.
__global__ __launch_bounds__(256) void k_mlp(const float* __restrict__ avg,
                                             const float* __restrict__ mx,
                                             const float* __restrict__ w1,   // [16,256]
                                             const float* __restrict__ w2,   // [256,16]
                                             float* __restrict__ chatt) {
    const int b = blockIdx.x, tid = threadIdx.x;
    __shared__ float sa[C], sx[C], h[16];
    sa[tid] = avg[b * C + tid];
    sx[tid] = mx[b * C + tid];
    __syncthreads();
    const int j = tid >> 4, sub = tid & 15;     // hidden unit j, lane-slice sub
    float pa = 0.f, pm = 0.f;
    #pragma unroll
    for (int c2 = sub; c2 < C; c2 += 16) {
        float w = w1[j * C + c2];
        pa += sa[c2] * w;
        pm += sx[c2] * w;
    }
    #pragma unroll
    for (int o = 8; o > 0; o >>= 1) {
        pa += __shfl_down(pa, o, 16);
        pm += __shfl_down(pm, o, 16);
    }
    if (sub == 0) h[j] = fmaxf(pa, 0.f) + fmaxf(pm, 0.f);
    __syncthreads();
    float o = 0.f;
    #pragma unroll
    for (int jj = 0; jj < 16; ++jj) o += h[jj] * w2[tid * 16 + jj];
    chatt[b * C + tid] = 1.0f / (1.0f + expf(-o));
}

// Pass 3: partial spatial mean/max over a 64-channel chunk of fp16 x * ch_att.
__global__ __launch_bounds__(256) void k_sp_partial(const vu4* __restrict__ x16,
                                                    const float* __restrict__ chatt,
                                                    float* __restrict__ pavg,
                                                    float* __restrict__ pmax) {
    const int blk   = blockIdx.x;
    const int chunk = blk & 3;
    const int tile  = (blk >> 2) & 7;
    const int b     = blk >> 5;
    const int tid   = threadIdx.x;
    const int g     = tile * 256 + tid;            // pixel-group (8 px), 0..2047
    float s[8];
    float m[8];
    #pragma unroll
    for (int k = 0; k < 8; ++k) { s[k] = 0.f; m[k] = -INFINITY; }
    const int c0 = chunk * 64;
    #pragma unroll 4
    for (int c = c0; c < c0 + 64; ++c) {
        vu4 u = x16[((size_t)(b * C + c)) * HW8 + g];
        const float a = chatt[b * C + c];
        #pragma unroll
        for (int q = 0; q < 4; ++q) {
            float2 f = h2f(u[q]);
            float y0 = f.x * a, y1 = f.y * a;
            s[2*q]   += y0;  s[2*q+1] += y1;
            m[2*q]   = fmaxf(m[2*q],   y0);
            m[2*q+1] = fmaxf(m[2*q+1], y1);
        }
    }
    vf4* pa = (vf4*)(pavg + ((size_t)(chunk * B + b)) * HW + g * 8);
    vf4* pm = (vf4*)(pmax + ((size_t)(chunk * B + b)) * HW + g * 8);
    vf4 a0 = {s[0], s[1], s[2], s[3]};
    vf4 a1 = {s[4], s[5], s[6], s[7]};
    vf4 m0 = {m[0], m[1], m[2], m[3]};
    vf4 m1 = {m[4], m[5], m[6], m[7]};
    pa[0] = a0; pa[1] = a1;
    pm[0] = m0; pm[1] = m1;
}

// Pass 4 (fused combine + 7x7 conv + sigmoid): each block produces a 16x16
// spatt tile from a 22x22 halo of combined maps (OOB = 0, zero-pad conv).
__global__ __launch_bounds__(256) void k_comb_conv(const float* __restrict__ pavg,
                                                   const float* __restrict__ pmax,
                                                   const float* __restrict__ wc,  // [1,2,7,7]
                                                   float* __restrict__ spatt) {
    const int blk = blockIdx.x;
    const int tx = blk & 7, ty = (blk >> 3) & 7, b = blk >> 6;
    __shared__ float sa[22][24], sm[22][24], swc[98];
    if (threadIdx.x < 98) swc[threadIdx.x] = wc[threadIdx.x];
    for (int idx = threadIdx.x; idx < 484; idx += 256) {
        const int ly = idx / 22, lx = idx - ly * 22;
        const int gy = ty * 16 + ly - 3, gx = tx * 16 + lx - 3;
        float s = 0.f, m = 0.f;
        if (gy >= 0 && gy < 128 && gx >= 0 && gx < 128) {
            const int p = gy * 128 + gx;
            float mm = -INFINITY;
            float ss = 0.f;
            #pragma unroll
            for (int ch = 0; ch < NCHUNK; ++ch) {
                ss += pavg[(size_t)(ch * B + b) * HW + p];
                mm = fmaxf(mm, pmax[(size_t)(ch * B + b) * HW + p]);
            }
            s = ss * (1.0f / C);
            m = mm;
        }
        sa[ly][lx] = s;
        sm[ly][lx] = m;
    }
    __syncthreads();
    const int px = threadIdx.x & 15, py = threadIdx.x >> 4;
    float acc = 0.f;
    #pragma unroll
    for (int kh = 0; kh < 7; ++kh) {
        #pragma unroll
        for (int kw = 0; kw < 7; ++kw) {
            acc += sa[py + kh][px + kw] * swc[kh * 7 + kw]
                 + sm[py + kh][px + kw] * swc[49 + kh * 7 + kw];
        }
    }
    spatt[(size_t)b * HW + (ty * 16 + py) * 128 + tx * 16 + px] =
        1.0f / (1.0f + expf(-acc));
}

// Pass 5: out = fp16(x) * ch_att[b,c] * sp_att[b,p]. NT loads on x16 (cache
// hint only), PLAIN stores on out (A/B vs round 5: NT stores suspected slow;
// out is never re-read and this is the last kernel, so allocation is harmless).
__global__ __launch_bounds__(256) void k_final(const vu4* __restrict__ x16,
                                               const float* __restrict__ chatt,
                                               const vf4* __restrict__ spatt,
                                               vf4* __restrict__ out) {
    const size_t total  = (size_t)B * C * HW8;       // 8M vu4 groups (8 px each)
    const size_t stride = (size_t)gridDim.x * 256;
    for (size_t f = (size_t)blockIdx.x * 256 + threadIdx.x; f < total; f += stride) {
        const size_t bc = f >> 11;                   // b*C + c
        const size_t g  = f & 2047;                  // pixel-group within image
        const size_t b  = bc >> 8;
        vu4 u = __builtin_nontemporal_load(&x16[f]);
        const float a = chatt[bc];
        vf4 sp0 = spatt[b * HW4 + g * 2];
        vf4 sp1 = spatt[b * HW4 + g * 2 + 1];
        float2 f0 = h2f(u.x);
        float2 f1 = h2f(u.y);
        float2 f2 = h2f(u.z);
        float2 f3 = h2f(u.w);
        vf4 r0, r1;
        r0.x = f0.x * a * sp0.x;  r0.y = f0.y * a * sp0.y;
        r0.z = f1.x * a * sp0.z;  r0.w = f1.y * a * sp0.w;
        r1.x = f2.x * a * sp1.x;  r1.y = f2.y * a * sp1.y;
        r1.z = f3.x * a * sp1.z;  r1.w = f3.y * a * sp1.w;
        out[f * 2]     = r0;
        out[f * 2 + 1] = r1;
    }
}

extern "C" void kernel_launch(void* const* d_in, const int* in_sizes, int n_in,
                              void* d_out, int out_size, void* d_ws, size_t ws_size,
                              hipStream_t stream) {
    const float* x  = (const float*)d_in[0];
    const float* w1 = (const float*)d_in[1];
    const float* w2 = (const float*)d_in[2];
    const float* wc = (const float*)d_in[3];
    vf4* out = (vf4*)d_out;
    char* ws = (char*)d_ws;

    // workspace layout
    vu2* x16  = (vu2*)ws;                                   // 128 MiB
    char* p = ws + (size_t)B * C * HW * 2;
    float* avg   = (float*)p;            p += 4096 * 4;     // [B,C]
    float* mx    = (float*)p;            p += 4096 * 4;
    float* chatt = (float*)p;            p += 4096 * 4;
    float* pavg  = (float*)p;            p += (size_t)NCHUNK * B * HW * 4;   // 4 MiB
    float* pmax  = (float*)p;            p += (size_t)NCHUNK * B * HW * 4;   // 4 MiB
    float* spatt = (float*)p;            p += (size_t)B * HW * 4;            // 1 MiB

    k_chan_stats_cast<<<B * C, 256, 0, stream>>>(x, x16, avg, mx);
    k_mlp<<<B, 256, 0, stream>>>(avg, mx, w1, w2, chatt);
    k_sp_partial<<<512, 256, 0, stream>>>((const vu4*)x16, chatt, pavg, pmax);
    k_comb_conv<<<1024, 256, 0, stream>>>(pavg, pmax, wc, spatt);
    k_final<<<4096, 256, 0, stream>>>((const vu4*)x16, chatt,
                                      (const vf4*)spatt, (vf4*)out);
}